// Round 5
// baseline (135.697 us; speedup 1.0000x reference)
//
#include <hip/hip_runtime.h>

typedef __bf16 bf16x8 __attribute__((ext_vector_type(8)));
typedef float f32x4 __attribute__((ext_vector_type(4)));

#define TWO_LOG2E 2.88539008177792681f   // 2*log2(e): exp(2x) = exp2(x*TWO_LOG2E)

#define GLOADLDS16(g, l) __builtin_amdgcn_global_load_lds(                     \
    (const __attribute__((address_space(1))) void*)(g),                        \
    (__attribute__((address_space(3))) void*)(l), 16, 0, 0)

__device__ __forceinline__ unsigned f2bf(float f) {
    unsigned u = __float_as_uint(f);
    return (u + 0x7FFFu + ((u >> 16) & 1u)) >> 16;   // RNE
}

// ---------------- kernel 1: row-normalize z=[z1;z2] -> bf16 zn[8192][256] ---------------
__global__ void __launch_bounds__(256) normalize_kernel(
    const float* __restrict__ z1, const float* __restrict__ z2,
    unsigned short* __restrict__ zn, float* __restrict__ S, float* __restrict__ out)
{
    if (blockIdx.x < 32) S[(blockIdx.x << 8) + threadIdx.x] = 0.f;
    if (blockIdx.x == 32 && threadIdx.x == 0) out[0] = 0.f;

    const int wave = threadIdx.x >> 6, lane = threadIdx.x & 63;
    const int row = (blockIdx.x << 2) + wave;               // 2048 blocks * 4 rows
    const float* src = (row < 4096) ? (z1 + row * 256) : (z2 + (row - 4096) * 256);
    float4 v = ((const float4*)src)[lane];                  // 64 lanes * 4 = 256
    float ss = v.x * v.x + v.y * v.y + v.z * v.z + v.w * v.w;
#pragma unroll
    for (int m = 32; m > 0; m >>= 1) ss += __shfl_xor(ss, m, 64);
    float sc = 1.0f / fmaxf(sqrtf(ss), 1e-8f);
    uint2 w;
    w.x = f2bf(v.x * sc) | (f2bf(v.y * sc) << 16);
    w.y = f2bf(v.z * sc) | (f2bf(v.w * sc) << 16);
    *(uint2*)(zn + row * 256 + (lane << 2)) = w;
}

// ---------------- kernel 2: 8-wave 256x512 tile, pipelined B-frags + setprio -----------
// R4 skeleton (XCD-pinned runs, parity staging, ring-4 depth-2 counted vmcnt) with the
// consume restructured into a 1-interval software pipeline:
//   stage(m+2); vmcnt(1)            (parity group g = wv>>2, wl = wv&3 picks quarter)
//   lgkmcnt(0)                      drains frags(m-1) ds_reads (issued ~1 interval ago)
//   s_barrier                       publishes chunk m (NEVER __syncthreads: vmcnt(0))
//   read bfN = frags(m)             4x ds_read_b128, consumer is NEXT interval
//   setprio(1); 8x MFMA on bfP (=frags(m-1)); setprio(0)   <- no lgkm wait needed
//   bfP = bfN                       static rotate (SSA-renamed, no copies)
// Hazards: RAW publish as R4 (staging group's vmcnt(1) precedes barrier(m)). WAR:
// reads(m) are lgkm0-drained before barrier(m+1); earliest rewrite of buffer m&3 is
// stage(m+4) issued after barrier(m+1) -> barrier-ordered, airtight.
// Epilogue shifts one interval late: chunk 4cc+3's MFMA lands at interval 4cc+4, so
// epilogue for col-chunk cc fires at kc==0 of cc+1 (14 in main loop + 1 in tail + final).
__global__ void __launch_bounds__(512, 4) simexp_kernel(
    const unsigned short* __restrict__ zn, float* __restrict__ S)
{
    __shared__ __align__(16) unsigned short Bs[4][2048];    // 4 x 4KB ring, block-shared

    const int tid = threadIdx.x;
    const int wv = tid >> 6, lane = tid & 63;
    const int q = lane >> 4, n16 = lane & 15;
    const int g = wv >> 2, wl = wv & 3;         // staging group / quarter within group
    const int bid = blockIdx.x;                 // 0..511
    const int run   = ((bid & 7) << 1) | ((bid >> 3) & 1);  // 0..15, 2 runs per XCD
    const int strip = bid >> 4;                 // 0..31
    const int rowBase = strip << 8;             // strip * 256
    const int colRun  = run << 9;               // run * 512
    const int rowW = rowBase + (wv << 5);       // this wave's 32 rows

    // A: 32 rows x K=256 in registers (frag: row=n16, k=q*8 within 32-elem step)
    bf16x8 a[2][8];
#pragma unroll
    for (int rt = 0; rt < 2; ++rt)
#pragma unroll
        for (int ks = 0; ks < 8; ++ks)
            a[rt][ks] = *(const bf16x8*)(zn + ((rowW + (rt << 4) + n16) << 8)
                                            + (ks << 5) + (q << 3));

    // stage this wave's quarter of chunk m (col-chunk m>>2, k-chunk m&3); 128B rows
    auto stage = [&](int m) {
        const int colBase = colRun + ((m >> 2) << 5);
        const int koff = (m & 3) << 6;
        unsigned short* base = &Bs[m & 3][0];
        int s = (wl << 6) + lane;               // 16B slot 0..255
        int c = s >> 3, d = s & 7;              // 8 consecutive lanes per row -> 128B
        int k8 = d ^ (c & 7);                   // XOR swizzle (conflict-free b128 reads)
        GLOADLDS16(zn + ((colBase + c) << 8) + koff + (k8 << 3), base + (s << 3));
    };

    float rs[2][4];
#pragma unroll
    for (int i = 0; i < 2; ++i)
#pragma unroll
        for (int j = 0; j < 4; ++j) rs[i][j] = 0.f;

    f32x4 acc[2][2];
    bf16x8 bfP[2][2], bfN[2][2];                // [ks][ct], prev / next frags

    auto readfrags = [&](int kc) {              // read chunk kc's frags (buffer kc&3==kc)
        const unsigned short* bb = &Bs[kc & 3][0];
#pragma unroll
        for (int ks = 0; ks < 2; ++ks)
#pragma unroll
            for (int ct = 0; ct < 2; ++ct) {
                int c  = (ct << 4) + n16;               // col 0..31
                int k8 = ((ks << 2) + q) ^ (c & 7);     // swizzled chunk
                bfN[ks][ct] = *(const bf16x8*)(bb + (((c << 3) + k8) << 3));
            }
    };
    auto mfmastep = [&](int kcP) {              // MFMA bfP (chunk with k-index kcP)
        __builtin_amdgcn_s_setprio(1);
#pragma unroll
        for (int ks = 0; ks < 2; ++ks)
#pragma unroll
            for (int rt = 0; rt < 2; ++rt)
#pragma unroll
                for (int ct = 0; ct < 2; ++ct)
                    acc[rt][ct] = __builtin_amdgcn_mfma_f32_16x16x32_bf16(
                        a[rt][(kcP << 1) + ks], bfP[ks][ct], acc[rt][ct], 0, 0, 0);
        __builtin_amdgcn_s_setprio(0);
    };
    auto rotate = [&]() {
#pragma unroll
        for (int ks = 0; ks < 2; ++ks)
#pragma unroll
            for (int ct = 0; ct < 2; ++ct) bfP[ks][ct] = bfN[ks][ct];
    };
    auto zacc = [&]() {
#pragma unroll
        for (int rt = 0; rt < 2; ++rt)
#pragma unroll
            for (int ct = 0; ct < 2; ++ct) acc[rt][ct] = (f32x4){0.f, 0.f, 0.f, 0.f};
    };
    auto epilogue = [&]() {
#pragma unroll
        for (int rt = 0; rt < 2; ++rt)
#pragma unroll
            for (int ct = 0; ct < 2; ++ct)
#pragma unroll
                for (int r = 0; r < 4; ++r)
                    rs[rt][r] += __builtin_amdgcn_exp2f(acc[rt][ct][r] * TWO_LOG2E);
    };

    zacc();
    // prologue: group 0 stages chunk 0, group 1 stages chunk 1 (parity-consistent)
    if (g == 0) stage(0); else stage(1);

    for (int cc = 0; cc < 15; ++cc) {            // intervals m = 4cc+kc, m = 0..59
#pragma unroll
        for (int kc = 0; kc < 4; ++kc) {
            if ((kc & 1) == g) {                 // wave-uniform branch
                stage((cc << 2) + kc + 2);
                asm volatile("s_waitcnt vmcnt(1)" ::: "memory");  // own chunk-m done
            }
            asm volatile("s_waitcnt lgkmcnt(0)" ::: "memory");    // drain frags(m-1)
            __builtin_amdgcn_s_barrier();
            asm volatile("" ::: "memory");       // keep ds_reads below the barrier
            readfrags(kc);
            if (kc == 0) {
                if (cc > 0) { mfmastep(3); epilogue(); zacc(); }  // finish col-chunk cc-1
            } else {
                mfmastep(kc - 1);
            }
            rotate();
        }
    }
    // tail: intervals m=60..63, then final MFMA of chunk 63
    // m=60 (kc=0): g0 stages 62
    if (g == 0) { stage(62); asm volatile("s_waitcnt vmcnt(1)" ::: "memory"); }
    asm volatile("s_waitcnt lgkmcnt(0)" ::: "memory");
    __builtin_amdgcn_s_barrier();
    asm volatile("" ::: "memory");
    readfrags(0);
    mfmastep(3); epilogue(); zacc();             // finish col-chunk 14
    rotate();
    // m=61 (kc=1): g1 stages 63
    if (g == 1) { stage(63); asm volatile("s_waitcnt vmcnt(1)" ::: "memory"); }
    asm volatile("s_waitcnt lgkmcnt(0)" ::: "memory");
    __builtin_amdgcn_s_barrier();
    asm volatile("" ::: "memory");
    readfrags(1);
    mfmastep(0);
    rotate();
    // m=62 (kc=2): g0 drains its last stage (chunk 62)
    if (g == 0) { asm volatile("s_waitcnt vmcnt(0)" ::: "memory"); }
    asm volatile("s_waitcnt lgkmcnt(0)" ::: "memory");
    __builtin_amdgcn_s_barrier();
    asm volatile("" ::: "memory");
    readfrags(2);
    mfmastep(1);
    rotate();
    // m=63 (kc=3): g1 drains its last stage (chunk 63)
    if (g == 1) { asm volatile("s_waitcnt vmcnt(0)" ::: "memory"); }
    asm volatile("s_waitcnt lgkmcnt(0)" ::: "memory");
    __builtin_amdgcn_s_barrier();
    asm volatile("" ::: "memory");
    readfrags(3);
    mfmastep(2);
    rotate();
    // final: MFMA chunk 63 (kcP=3), finish col-chunk 15
    asm volatile("s_waitcnt lgkmcnt(0)" ::: "memory");
    mfmastep(3);
    epilogue();

    // flush once per wave (C/D layout: col=n16, row=q*4+r)
#pragma unroll
    for (int rt = 0; rt < 2; ++rt)
#pragma unroll
        for (int r = 0; r < 4; ++r) {
            float s = rs[rt][r];
            s += __shfl_xor(s, 1, 64);
            s += __shfl_xor(s, 2, 64);
            s += __shfl_xor(s, 4, 64);
            s += __shfl_xor(s, 8, 64);
            if (n16 == 0) atomicAdd(&S[rowW + (rt << 4) + (q << 2) + r], s);
        }
}

// ---------------- kernel 3: loss = mean( log(S_i - e^{sim_ii}) - sim_{i,target} ) -------
__global__ void __launch_bounds__(256) finish_kernel(
    const unsigned short* __restrict__ zn, const float* __restrict__ S,
    float* __restrict__ out)
{
    __shared__ float vals[16];
    const int tid = threadIdx.x, lane = tid & 63, wave = tid >> 6;
    const int q = lane >> 4, n16 = lane & 15;
    const int rib = (wave << 2) + q;                // 0..15 rows per block
    const int row = (blockIdx.x << 4) + rib;        // 512 blocks * 16 rows
    const int tar = (row + 4096) & 8191;

    float drr = 0.f, drt = 0.f;
#pragma unroll
    for (int i = 0; i < 4; ++i) {
        int k = (i << 6) + (n16 << 2);
        uint2 ur = *(const uint2*)(zn + (row << 8) + k);
        uint2 ut = *(const uint2*)(zn + (tar << 8) + k);
        float a0 = __uint_as_float(ur.x << 16),  a1 = __uint_as_float(ur.x & 0xFFFF0000u);
        float a2 = __uint_as_float(ur.y << 16),  a3 = __uint_as_float(ur.y & 0xFFFF0000u);
        float b0 = __uint_as_float(ut.x << 16),  b1 = __uint_as_float(ut.x & 0xFFFF0000u);
        float b2 = __uint_as_float(ut.y << 16),  b3 = __uint_as_float(ut.y & 0xFFFF0000u);
        drr += a0 * a0 + a1 * a1 + a2 * a2 + a3 * a3;
        drt += a0 * b0 + a1 * b1 + a2 * b2 + a3 * b3;
    }
#pragma unroll
    for (int m = 1; m <= 8; m <<= 1) {
        drr += __shfl_xor(drr, m, 64);
        drt += __shfl_xor(drt, m, 64);
    }
    if (n16 == 0) {
        float Sv = S[row] - __builtin_amdgcn_exp2f(drr * TWO_LOG2E);  // remove diagonal
        vals[rib] = 0.693147180559945f * __builtin_amdgcn_logf(Sv) - 2.0f * drt;
    }
    __syncthreads();
    if (tid == 0) {
        float s = 0.f;
#pragma unroll
        for (int i = 0; i < 16; ++i) s += vals[i];
        atomicAdd(out, s * (1.0f / 8192.0f));
    }
}

extern "C" void kernel_launch(void* const* d_in, const int* in_sizes, int n_in,
                              void* d_out, int out_size, void* d_ws, size_t ws_size,
                              hipStream_t stream)
{
    const float* z1 = (const float*)d_in[0];
    const float* z2 = (const float*)d_in[1];
    unsigned short* zn = (unsigned short*)d_ws;                              // 4 MB
    float* S = (float*)((char*)d_ws + 8192 * 256 * sizeof(unsigned short));  // 32 KB
    float* out = (float*)d_out;

    normalize_kernel<<<2048, 256, 0, stream>>>(z1, z2, zn, S, out);
    simexp_kernel<<<512, 512, 0, stream>>>(zn, S);
    finish_kernel<<<512, 256, 0, stream>>>(zn, S, out);
}

// Round 6
// 110.300 us; speedup vs baseline: 1.2303x; 1.2303x over previous
//
#include <hip/hip_runtime.h>

typedef __bf16 bf16x8 __attribute__((ext_vector_type(8)));
typedef float f32x4 __attribute__((ext_vector_type(4)));

#define TWO_LOG2E 2.88539008177792681f   // 2*log2(e): exp(2x) = exp2(x*TWO_LOG2E)

#define GLOADLDS16(g, l) __builtin_amdgcn_global_load_lds(                     \
    (const __attribute__((address_space(1))) void*)(g),                        \
    (__attribute__((address_space(3))) void*)(l), 16, 0, 0)

__device__ __forceinline__ unsigned f2bf(float f) {
    unsigned u = __float_as_uint(f);
    return (u + 0x7FFFu + ((u >> 16) & 1u)) >> 16;   // RNE
}

// ---------------- kernel 1: row-normalize z=[z1;z2] -> bf16 zn[8192][256] ---------------
__global__ void __launch_bounds__(256) normalize_kernel(
    const float* __restrict__ z1, const float* __restrict__ z2,
    unsigned short* __restrict__ zn, float* __restrict__ S, float* __restrict__ out)
{
    if (blockIdx.x < 32) S[(blockIdx.x << 8) + threadIdx.x] = 0.f;
    if (blockIdx.x == 32 && threadIdx.x == 0) out[0] = 0.f;

    const int wave = threadIdx.x >> 6, lane = threadIdx.x & 63;
    const int row = (blockIdx.x << 2) + wave;               // 2048 blocks * 4 rows
    const float* src = (row < 4096) ? (z1 + row * 256) : (z2 + (row - 4096) * 256);
    float4 v = ((const float4*)src)[lane];                  // 64 lanes * 4 = 256
    float ss = v.x * v.x + v.y * v.y + v.z * v.z + v.w * v.w;
#pragma unroll
    for (int m = 32; m > 0; m >>= 1) ss += __shfl_xor(ss, m, 64);
    float sc = 1.0f / fmaxf(sqrtf(ss), 1e-8f);
    uint2 w;
    w.x = f2bf(v.x * sc) | (f2bf(v.y * sc) << 16);
    w.y = f2bf(v.z * sc) | (f2bf(v.w * sc) << 16);
    *(uint2*)(zn + row * 256 + (lane << 2)) = w;
}

// ---------------- kernel 2: SYMMETRIC upper-triangle tiling, R4-proven tile body -------
// exp(sim) is symmetric -> compute only tiles (ti<=tj) of the 32x32 grid of 256x256
// tiles and scatter both ways: row-sums -> S[rows] (as before) and per-column sums ->
// S[cols] (the mirror entries) via cs[2] + q-shuffle + atomicAdd per col-chunk.
// Work = 528/1024 = 52% of R4. Jobs: 0..495 = off-diag pairs (ti<tj); 496..511 =
// dual-diagonal blocks handling diag tiles (2j, 2j+1) back-to-back (512 blocks total,
// 2/CU, no straggler round). Diag tiles: wave wv computes only col-chunks cc>=wv;
// cc==wv (contains both orderings of each pair) takes row path only; cc>wv both paths.
// Every matrix entry lands in S exactly once (verified chunk-case analysis).
//
// Tile body = R4's proven skeleton at 32 intervals: chunk = 32 cols x 64 k (4KB),
// ring of 4, depth-2, parity staging (group g=wv>>2 stages parity-g chunks, wl=wv&3
// picks the quarter, 128B-contiguous rows), counted `s_waitcnt vmcnt(1)`, raw
// s_barrier publish. NEVER __syncthreads. NO pipeline registers (R5 spilled: +32 VGPRs
// over the 128 cap -> 30MB scratch writes; this version adds only 2 scalars).
// Epilogue is guarded by the same `act` as consume: exp(0)=1 would poison rs.
// Inter-tile WAR (dual blocks): tile-1's stage(0) is issued only after that wave passed
// tile-0's barriers m=29..31, which postdate all Bs[0] reads (m=28) -- barrier-ordered.
__global__ void __launch_bounds__(512, 4) simexp_kernel(
    const unsigned short* __restrict__ zn, float* __restrict__ S)
{
    __shared__ __align__(16) unsigned short Bs[4][2048];    // 4 x 4KB ring, block-shared

    const int tid = threadIdx.x;
    const int wv = tid >> 6, lane = tid & 63;
    const int q = lane >> 4, n16 = lane & 15;
    const int g = wv >> 2, wl = wv & 3;         // staging group / quarter within group

    int ti, tj, nrep = 1;
    {
        int job = blockIdx.x;                   // 0..511
        if (job < 496) {                        // off-diag pair, ti<tj
            int t = 0, rem = job;
            while (rem >= 31 - t) { rem -= 31 - t; ++t; }   // uniform, <=31 iters
            ti = t; tj = t + 1 + rem;
        } else {                                // dual-diagonal block
            ti = tj = (job - 496) << 1;
            nrep = 2;
        }
    }

    for (int rep = 0; rep < nrep; ++rep) {
        const int rT = ti + rep, cT = tj + rep; // off-diag: rep==0 -> (ti,tj)
        const bool diag = (rT == cT);
        const int colTile = cT << 8;
        const int rowW = (rT << 8) + (wv << 5); // this wave's 32 rows

        // A: 32 rows x K=256 in registers (frag: row=n16, k=q*8 within 32-elem step)
        bf16x8 a[2][8];
#pragma unroll
        for (int rt = 0; rt < 2; ++rt)
#pragma unroll
            for (int ks = 0; ks < 8; ++ks)
                a[rt][ks] = *(const bf16x8*)(zn + ((rowW + (rt << 4) + n16) << 8)
                                                + (ks << 5) + (q << 3));

        // stage quarter of chunk m (col-chunk m>>2, k-chunk m&3); 128B-contiguous rows
        auto stage = [&](int m) {
            const int colBase = colTile + ((m >> 2) << 5);
            const int koff = (m & 3) << 6;
            unsigned short* base = &Bs[m & 3][0];
            int s = (wl << 6) + lane;           // 16B slot 0..255
            int c = s >> 3, d = s & 7;          // 8 consecutive lanes per row -> 128B
            int k8 = d ^ (c & 7);               // XOR swizzle (conflict-free b128 reads)
            GLOADLDS16(zn + ((colBase + c) << 8) + koff + (k8 << 3), base + (s << 3));
        };

        float rs[2][4];
#pragma unroll
        for (int i = 0; i < 2; ++i)
#pragma unroll
            for (int j = 0; j < 4; ++j) rs[i][j] = 0.f;

        f32x4 acc[2][2];
        auto consume = [&](int kc) {            // buffer kc (m&3==kc since m=cc*4+kc)
            const unsigned short* bb = &Bs[kc & 3][0];
#pragma unroll
            for (int ks = 0; ks < 2; ++ks) {
                bf16x8 bf[2];
#pragma unroll
                for (int ct = 0; ct < 2; ++ct) {
                    int c  = (ct << 4) + n16;               // col 0..31
                    int k8 = ((ks << 2) + q) ^ (c & 7);     // swizzled chunk
                    bf[ct] = *(const bf16x8*)(bb + (((c << 3) + k8) << 3));
                }
#pragma unroll
                for (int rt = 0; rt < 2; ++rt)
#pragma unroll
                    for (int ct = 0; ct < 2; ++ct)
                        acc[rt][ct] = __builtin_amdgcn_mfma_f32_16x16x32_bf16(
                            a[rt][(kc << 1) + ks], bf[ct], acc[rt][ct], 0, 0, 0);
            }
        };
        auto zacc = [&]() {
#pragma unroll
            for (int rt = 0; rt < 2; ++rt)
#pragma unroll
                for (int ct = 0; ct < 2; ++ct) acc[rt][ct] = (f32x4){0.f, 0.f, 0.f, 0.f};
        };
        // epilogue: row-sums into rs; col-sums cs[2] reduced over q and flushed now
        auto epiRC = [&](bool doCol, int ccc) {
            float cs[2] = {0.f, 0.f};
#pragma unroll
            for (int rt = 0; rt < 2; ++rt)
#pragma unroll
                for (int ct = 0; ct < 2; ++ct)
#pragma unroll
                    for (int r = 0; r < 4; ++r) {
                        float e = __builtin_amdgcn_exp2f(acc[rt][ct][r] * TWO_LOG2E);
                        rs[rt][r] += e;
                        cs[ct] += e;
                    }
            if (doCol) {
#pragma unroll
                for (int ct = 0; ct < 2; ++ct) {
                    float s = cs[ct];
                    s += __shfl_xor(s, 16, 64);             // reduce over q
                    s += __shfl_xor(s, 32, 64);
                    if (lane < 16)                          // q==0 lanes
                        atomicAdd(&S[colTile + (ccc << 5) + (ct << 4) + n16], s);
                }
            }
        };

        // prologue: group 0 stages chunk 0, group 1 stages chunk 1
        if (g == 0) stage(0); else stage(1);

        for (int cc = 0; cc < 7; ++cc) {         // intervals m=cc*4+kc, m=0..27
            zacc();
            const bool act   = !diag || (cc >= wv);   // wave-uniform
            const bool doCol = !diag || (cc >  wv);
#pragma unroll
            for (int kc = 0; kc < 4; ++kc) {
                if ((kc & 1) == g) {             // wave-uniform branch
                    stage((cc << 2) + kc + 2);
                    asm volatile("s_waitcnt vmcnt(1)" ::: "memory");  // own chunk-m done
                }
                __builtin_amdgcn_s_barrier();
                asm volatile("" ::: "memory");   // keep ds_reads below the barrier
                if (act) consume(kc);
            }
            if (act) epiRC(doCol, cc);
        }
        // peeled tail cc=7 (act always true: wv<=7); chunks 28..31
        zacc();
        if (g == 0) { stage(30); asm volatile("s_waitcnt vmcnt(1)" ::: "memory"); }
        __builtin_amdgcn_s_barrier();
        asm volatile("" ::: "memory");
        consume(0);
        if (g == 1) { stage(31); asm volatile("s_waitcnt vmcnt(1)" ::: "memory"); }
        __builtin_amdgcn_s_barrier();
        asm volatile("" ::: "memory");
        consume(1);
        if (g == 0) { asm volatile("s_waitcnt vmcnt(0)" ::: "memory"); }
        __builtin_amdgcn_s_barrier();
        asm volatile("" ::: "memory");
        consume(2);
        if (g == 1) { asm volatile("s_waitcnt vmcnt(0)" ::: "memory"); }
        __builtin_amdgcn_s_barrier();
        asm volatile("" ::: "memory");
        consume(3);
        epiRC(!diag || (wv < 7), 7);

        // row flush (C/D layout: col=n16, row=q*4+r)
#pragma unroll
        for (int rt = 0; rt < 2; ++rt)
#pragma unroll
            for (int r = 0; r < 4; ++r) {
                float s = rs[rt][r];
                s += __shfl_xor(s, 1, 64);
                s += __shfl_xor(s, 2, 64);
                s += __shfl_xor(s, 4, 64);
                s += __shfl_xor(s, 8, 64);
                if (n16 == 0) atomicAdd(&S[rowW + (rt << 4) + (q << 2) + r], s);
            }
    }
}

// ---------------- kernel 3: loss = mean( log(S_i - e^{sim_ii}) - sim_{i,target} ) -------
__global__ void __launch_bounds__(256) finish_kernel(
    const unsigned short* __restrict__ zn, const float* __restrict__ S,
    float* __restrict__ out)
{
    __shared__ float vals[16];
    const int tid = threadIdx.x, lane = tid & 63, wave = tid >> 6;
    const int q = lane >> 4, n16 = lane & 15;
    const int rib = (wave << 2) + q;                // 0..15 rows per block
    const int row = (blockIdx.x << 4) + rib;        // 512 blocks * 16 rows
    const int tar = (row + 4096) & 8191;

    float drr = 0.f, drt = 0.f;
#pragma unroll
    for (int i = 0; i < 4; ++i) {
        int k = (i << 6) + (n16 << 2);
        uint2 ur = *(const uint2*)(zn + (row << 8) + k);
        uint2 ut = *(const uint2*)(zn + (tar << 8) + k);
        float a0 = __uint_as_float(ur.x << 16),  a1 = __uint_as_float(ur.x & 0xFFFF0000u);
        float a2 = __uint_as_float(ur.y << 16),  a3 = __uint_as_float(ur.y & 0xFFFF0000u);
        float b0 = __uint_as_float(ut.x << 16),  b1 = __uint_as_float(ut.x & 0xFFFF0000u);
        float b2 = __uint_as_float(ut.y << 16),  b3 = __uint_as_float(ut.y & 0xFFFF0000u);
        drr += a0 * a0 + a1 * a1 + a2 * a2 + a3 * a3;
        drt += a0 * b0 + a1 * b1 + a2 * b2 + a3 * b3;
    }
#pragma unroll
    for (int m = 1; m <= 8; m <<= 1) {
        drr += __shfl_xor(drr, m, 64);
        drt += __shfl_xor(drt, m, 64);
    }
    if (n16 == 0) {
        float Sv = S[row] - __builtin_amdgcn_exp2f(drr * TWO_LOG2E);  // remove diagonal
        vals[rib] = 0.693147180559945f * __builtin_amdgcn_logf(Sv) - 2.0f * drt;
    }
    __syncthreads();
    if (tid == 0) {
        float s = 0.f;
#pragma unroll
        for (int i = 0; i < 16; ++i) s += vals[i];
        atomicAdd(out, s * (1.0f / 8192.0f));
    }
}

extern "C" void kernel_launch(void* const* d_in, const int* in_sizes, int n_in,
                              void* d_out, int out_size, void* d_ws, size_t ws_size,
                              hipStream_t stream)
{
    const float* z1 = (const float*)d_in[0];
    const float* z2 = (const float*)d_in[1];
    unsigned short* zn = (unsigned short*)d_ws;                              // 4 MB
    float* S = (float*)((char*)d_ws + 8192 * 256 * sizeof(unsigned short));  // 32 KB
    float* out = (float*)d_out;

    normalize_kernel<<<2048, 256, 0, stream>>>(z1, z2, zn, S, out);
    simexp_kernel<<<512, 512, 0, stream>>>(zn, S);
    finish_kernel<<<512, 256, 0, stream>>>(zn, S, out);
}